// Round 5
// baseline (1277.425 us; speedup 1.0000x reference)
//
#include <hip/hip_runtime.h>
#include <hip/hip_fp16.h>

#define IN_F   8192
#define OUT_F  28672
#define NFP    128
#define NB     32            // B*S rows
#define KQTOT  (IN_F / 4)    // 2048 packed dwords per batch row

// ws layout (bytes):
//   q_pk : int  [NB][KQTOT]  (batch-major, 4 int8 per dword along k)  [0, 262144)
//   xs   : float[32]                                                  [262144, ...)
//   act  : float[32][128]                                             [263168, ...)
#define WS_QPK 0
#define WS_XS  262144
#define WS_ACT 263168

typedef int v4i  __attribute__((ext_vector_type(4)));
typedef int v16i __attribute__((ext_vector_type(16)));

__device__ __forceinline__ int pack8(int4 v) {
    return (v.x & 0xFF) | ((v.y & 0xFF) << 8) | ((v.z & 0xFF) << 16) | (v.w << 24);
}

// ---------------- Kernel A: dynamic quantization (unchanged) ----------------
__global__ __launch_bounds__(256) void quant_kernel(
    const float* __restrict__ x, const int* __restrict__ ind,
    int* __restrict__ q_pk, float* __restrict__ xs_out,
    float* __restrict__ act_out)
{
    __shared__ unsigned char flags[IN_F];   // 8 KB
    __shared__ float redbuf[4];
    __shared__ float xs_sh;
    const int tid = threadIdx.x;
    const int b = blockIdx.x;

    int* fl4 = (int*)flags;
    for (int i = tid; i < IN_F / 4; i += 256) fl4[i] = 0;
    __syncthreads();
    if (tid < NFP) flags[ind[tid]] = 1;
    __syncthreads();

    const float* xrow = x + (size_t)b * IN_F;
    const float4* x4 = (const float4*)xrow;
    float mx = 0.f;
    for (int c = tid; c < IN_F / 4; c += 256) {
        float4 v = x4[c];
        int fw = fl4[c];
        if (!(fw & 0x000000FF)) mx = fmaxf(mx, fabsf(v.x));
        if (!(fw & 0x0000FF00)) mx = fmaxf(mx, fabsf(v.y));
        if (!(fw & 0x00FF0000)) mx = fmaxf(mx, fabsf(v.z));
        if (!(fw & 0xFF000000)) mx = fmaxf(mx, fabsf(v.w));
    }
    #pragma unroll
    for (int off = 32; off > 0; off >>= 1) {
        float o = __shfl_down(mx, off, 64);
        mx = o > mx ? o : mx;
    }
    if ((tid & 63) == 0) redbuf[tid >> 6] = mx;
    __syncthreads();
    if (tid == 0) {
        float m = redbuf[0];
        #pragma unroll
        for (int i = 1; i < 4; i++) m = redbuf[i] > m ? redbuf[i] : m;
        float xs = __half2float(__float2half_rn(m / 127.0f));   // x_scale = f16(max/127)
        xs_sh = xs;
        xs_out[b] = xs;
    }
    __syncthreads();
    const float xs = xs_sh;

    for (int c = tid; c < IN_F / 4; c += 256) {
        float4 v = x4[c];
        int fw = fl4[c];
        float ee[4];
        ee[0] = (fw & 0x000000FF) ? 0.f : v.x;
        ee[1] = (fw & 0x0000FF00) ? 0.f : v.y;
        ee[2] = (fw & 0x00FF0000) ? 0.f : v.z;
        ee[3] = (fw & 0xFF000000) ? 0.f : v.w;
        int pk = 0;
        #pragma unroll
        for (int j = 0; j < 4; j++) {
            // q = clip(rint(f16(v / xs)), -128, 127)
            float qf = __half2float(__float2half_rn(ee[j] / xs));
            float r = rintf(qf);
            r = fminf(fmaxf(r, -128.f), 127.f);
            int qi = (int)r;
            pk |= (qi & 0xFF) << (8 * j);
        }
        q_pk[(size_t)b * KQTOT + c] = pk;
    }
    if (tid < NFP) act_out[b * NFP + tid] = xrow[ind[tid]];
}

// ---------------- Kernel B: barrier-free streaming MFMA GEMM ----------------
// 896 blocks x 256 thr. Block owns 32 output features; its 4 waves split K in
// quarters (2048 each). B-fragments come straight from global W (pack in regs),
// A-fragments straight from L2-resident q_pk. One LDS reduction at the end.
#define KCHUNK 2048
#define KSTEPS (KCHUNK / 32)    // 64 MFMA steps per wave

__global__ __launch_bounds__(256, 3) void gemm_kernel(
    const int* __restrict__ w, const int* __restrict__ q_pk,
    const float* __restrict__ xs_ws, const float* __restrict__ act_ws,
    const float* __restrict__ sc, const float* __restrict__ wc,
    const float* __restrict__ bias, float* __restrict__ out)
{
    __shared__ int red[4][16][64];   // 16 KB: [k-chunk wave][acc reg][lane]

    const int tid  = threadIdx.x;
    const int wave = tid >> 6;
    const int lane = tid & 63;
    const int col  = lane & 31;     // output col within tile == A row (batch)
    const int half = lane >> 5;     // k-half selector

    const int nb = blockIdx.x * 32;
    const int n  = nb + col;        // this lane's output feature

    const int kbase = wave * KCHUNK;
    const int* wptr = w    + (size_t)n * IN_F + kbase + half * 16;
    const int* qptr = q_pk + (size_t)col * KQTOT + (kbase >> 2) + half * 4;

    v16i acc;
    #pragma unroll
    for (int r = 0; r < 16; r++) acc[r] = 0;

    #pragma unroll 4
    for (int s = 0; s < KSTEPS; s++) {
        int4 w0 = *(const int4*)(wptr + s * 32 + 0);
        int4 w1 = *(const int4*)(wptr + s * 32 + 4);
        int4 w2 = *(const int4*)(wptr + s * 32 + 8);
        int4 w3 = *(const int4*)(wptr + s * 32 + 12);
        v4i a = *(const v4i*)(qptr + s * 8);
        v4i b;
        b[0] = pack8(w0); b[1] = pack8(w1); b[2] = pack8(w2); b[3] = pack8(w3);
        acc = __builtin_amdgcn_mfma_i32_32x32x32_i8(a, b, acc, 0, 0, 0);
    }

    // cross-wave K reduction: r-major layout -> conflict-free lane-consecutive
    #pragma unroll
    for (int r = 0; r < 16; r++) red[wave][r][lane] = acc[r];
    __syncthreads();

    int sum[4];
    int bidx[4];
    #pragma unroll
    for (int j = 0; j < 4; j++) {
        const int r = wave * 4 + j;
        sum[j] = red[0][r][lane] + red[1][r][lane] + red[2][r][lane] + red[3][r][lane];
        bidx[j] = j + 8 * wave + 4 * half;   // C/D row = (r&3) + 8*(r>>2) + 4*half
    }

    // -------- epilogue: f32 (ref overflows f16 -> threshold inf; keep finite) ----
    const float scn = sc[n];
    const float bin = bias[n];
    const float* wcn = wc + (size_t)n * NFP;

    float dots[4] = {0.f, 0.f, 0.f, 0.f};
    for (int t = 0; t < NFP; t += 4) {
        float4 wv4 = *(const float4*)(wcn + t);
        #pragma unroll
        for (int j = 0; j < 4; j++) {
            float4 av = *(const float4*)(act_ws + bidx[j] * NFP + t);
            dots[j] += av.x * wv4.x + av.y * wv4.y + av.z * wv4.z + av.w * wv4.w;
        }
    }

    #pragma unroll
    for (int j = 0; j < 4; j++) {
        const int b = bidx[j];
        out[(size_t)b * OUT_F + n] = (float)sum[j] * xs_ws[b] * scn + dots[j] + bin;
    }
}

extern "C" void kernel_launch(void* const* d_in, const int* in_sizes, int n_in,
                              void* d_out, int out_size, void* d_ws, size_t ws_size,
                              hipStream_t stream) {
    const float* x    = (const float*)d_in[0];
    const int*   wgt  = (const int*)d_in[1];
    const float* scol = (const float*)d_in[2];
    const float* wch  = (const float*)d_in[3];
    const float* bias = (const float*)d_in[4];
    const int*   ind  = (const int*)d_in[5];
    float* out = (float*)d_out;

    int*   q_pk = (int*)((char*)d_ws + WS_QPK);
    float* xs   = (float*)((char*)d_ws + WS_XS);
    float* act  = (float*)((char*)d_ws + WS_ACT);

    quant_kernel<<<NB, 256, 0, stream>>>(x, ind, q_pk, xs, act);
    gemm_kernel<<<OUT_F / 32, 256, 0, stream>>>(wgt, q_pk, xs, act, scol, wch, bias, out);
}